// Round 13
// baseline (477.166 us; speedup 1.0000x reference)
//
#include <hip/hip_runtime.h>
#include <hip/hip_bf16.h>
#include <hip/hip_fp16.h>
#include <stdint.h>

typedef float    f32x4 __attribute__((ext_vector_type(4)));
typedef float    fvec4 __attribute__((ext_vector_type(4)));
typedef _Float16 f16x8 __attribute__((ext_vector_type(8)));

#define D_MODEL 1024
#define D_FF    4096
#define NTOK    8192
#define CAP_ROWS 16896  // 132 * 128
#define NRB      132    // row blocks of 128

// ---- workspace layout (bytes) ----
#define OFF_W1  0UL           // 4*4096*1024*2 (W1^T fp16: [e][n][k])
#define OFF_W2  33554432UL    // 4*1024*4096*2 (W2^T fp16: [e][d][f])
#define OFF_XG  67108864UL    // x16 [8192][1024] fp16 (16MB); then Eout [CAP_ROWS][1024] fp16
#define OFF_H   101711872UL   // 16896*4096*2
#define OFF_CNT 240123904UL
#define OFF_OFS 240123936UL
#define OFF_TOK 240124160UL
#define OFF_E12 240259328UL   // e12 during routing; rewritten as sl12 by plan_k
#define OFF_W12 240292096UL
#define WS_NEED 240357632UL

__device__ __forceinline__ void gload_lds16(const void* g, void* l) {
  __builtin_amdgcn_global_load_lds(
      (const __attribute__((address_space(1))) unsigned int*)g,
      (__attribute__((address_space(3))) unsigned int*)l, 16, 0, 0);
}

// fast tanh-approx GELU (inf-safe), max err ~3e-4
__device__ __forceinline__ float fast_gelu(float v) {
  float v2 = v * v;
  float y2 = v * (2.302118131f + 0.10293924f * v2);
  float t = exp2f(y2);
  return v - v * __builtin_amdgcn_rcpf(1.f + t);
}

// shared transpose-convert body: one 64x64 tile of in[e][K][N] fp32 -> out[e][N][K] fp16
// t in [0,256), tile = 64x65 float scratch
__device__ __forceinline__ void wtrans_body(
    const float* __restrict__ in, _Float16* __restrict__ out,
    int K, int N, int e, int n0, int k0, int t, float (*tile)[65]) {
  const float* src = in + (size_t)e * K * N;
  _Float16* dst = out + (size_t)e * K * N;
  {
    int kk = t >> 2, nc = (t & 3) * 16;
    const float* p = src + (size_t)(k0 + kk) * N + n0 + nc;
#pragma unroll
    for (int j = 0; j < 4; ++j) {
      fvec4 v = *(const fvec4*)(p + j * 4);
      tile[kk][nc + j * 4 + 0] = v[0]; tile[kk][nc + j * 4 + 1] = v[1];
      tile[kk][nc + j * 4 + 2] = v[2]; tile[kk][nc + j * 4 + 3] = v[3];
    }
  }
  __syncthreads();
  {
    int nn = t >> 2, kb = (t & 3) * 16;
    f16x8 o0, o1;
#pragma unroll
    for (int j = 0; j < 8; ++j) o0[j] = (_Float16)tile[kb + j][nn];
#pragma unroll
    for (int j = 0; j < 8; ++j) o1[j] = (_Float16)tile[kb + 8 + j][nn];
    _Float16* q = dst + (size_t)(n0 + nn) * K + k0 + kb;
    *(f16x8*)q = o0;
    *((f16x8*)q + 1) = o1;
  }
  __syncthreads();
}

// ---- kernel 1: router (0..2047) + W1^T (2048..6143) + x->fp16 cvt (6144..10239) ----
__global__ __launch_bounds__(256) void rwc_k(
    const float* __restrict__ x, const float* __restrict__ Wr,
    const float* __restrict__ br, int* __restrict__ e12,
    float* __restrict__ w12,
    const float* __restrict__ W1, _Float16* __restrict__ W1f,
    _Float16* __restrict__ x16) {
  __shared__ float tile[64][65];
  int b = blockIdx.x;
  if (b >= 6144) {
    int row = (b - 6144) * 2 + (threadIdx.x >> 7);
    int tid = threadIdx.x & 127;
    const float* src = x + (size_t)row * D_MODEL + tid * 8;
    fvec4 v0 = *(const fvec4*)src;
    fvec4 v1 = *(const fvec4*)(src + 4);
    f16x8 o;
#pragma unroll
    for (int j = 0; j < 4; ++j) { o[j] = (_Float16)v0[j]; o[4 + j] = (_Float16)v1[j]; }
    *(f16x8*)(x16 + (size_t)row * D_MODEL + tid * 8) = o;
    return;
  }
  if (b >= 2048) {
    int bb = b - 2048;   // W1: K=1024, N=4096; 64(n) x 16(k) x 4(e)
    int n0 = (bb & 63) * 64, k0 = ((bb >> 6) & 15) * 64, e = bb >> 10;
    wtrans_body(W1, W1f, 1024, 4096, e, n0, k0, threadIdx.x, tile);
    return;
  }
  int wid = threadIdx.x >> 6, lane = threadIdx.x & 63;
  int t = b * 4 + wid;
  const float* xr = x + (size_t)t * D_MODEL;
  float a0 = 0.f, a1 = 0.f, a2 = 0.f, a3 = 0.f;
#pragma unroll
  for (int c = 0; c < 4; ++c) {
    int d0 = c * 256 + lane * 4;
    fvec4 xv = *(const fvec4*)(xr + d0);
#pragma unroll
    for (int j = 0; j < 4; ++j) {
      fvec4 wv = *(const fvec4*)(Wr + (size_t)(d0 + j) * 4);
      a0 += xv[j] * wv[0]; a1 += xv[j] * wv[1];
      a2 += xv[j] * wv[2]; a3 += xv[j] * wv[3];
    }
  }
#pragma unroll
  for (int m = 32; m; m >>= 1) {
    a0 += __shfl_xor(a0, m, 64); a1 += __shfl_xor(a1, m, 64);
    a2 += __shfl_xor(a2, m, 64); a3 += __shfl_xor(a3, m, 64);
  }
  if (lane == 0) {
    float l[4] = {a0 + br[0], a1 + br[1], a2 + br[2], a3 + br[3]};
    int e1 = 0; float m1 = l[0];
#pragma unroll
    for (int e = 1; e < 4; ++e) if (l[e] > m1) { m1 = l[e]; e1 = e; }
    int e2 = -1; float m2 = -1e30f;
#pragma unroll
    for (int e = 0; e < 4; ++e) if (e != e1 && l[e] > m2) { m2 = l[e]; e2 = e; }
    float tt = expf(m2 - m1);
    float w1 = 1.f / (1.f + tt), w2 = tt / (1.f + tt);
    e12[t] = e1 | (e2 << 8);
    w12[2 * t] = w1; w12[2 * t + 1] = w2;
  }
}

// ---- kernel 2: plan (deterministic; writes sl12 into e12 buf; zero-fills pad tok) ----
__global__ __launch_bounds__(256) void plan_k(
    int* __restrict__ e12, const float* __restrict__ w12,
    int* __restrict__ counts, int* __restrict__ offs,
    int* __restrict__ tok) {
  __shared__ int ls[4][256];
  __shared__ int lt[4];
  __shared__ int lo[5];
  int tid = threadIdx.x;
  int t0 = tid * 32;
  int pe[32];
  int c0 = 0, c1 = 0, c2 = 0, c3 = 0;
#pragma unroll
  for (int j = 0; j < 32; ++j) {
    int p = e12[t0 + j];
    pe[j] = p;
    int e1 = p & 255, e2 = p >> 8;
    c0 += (e1 == 0) + (e2 == 0);
    c1 += (e1 == 1) + (e2 == 1);
    c2 += (e1 == 2) + (e2 == 2);
    c3 += (e1 == 3) + (e2 == 3);
  }
  ls[0][tid] = c0; ls[1][tid] = c1; ls[2][tid] = c2; ls[3][tid] = c3;
  __syncthreads();
  int wv = tid >> 6, lane = tid & 63;
  {
    int s0 = ls[wv][lane * 4 + 0], s1 = ls[wv][lane * 4 + 1];
    int s2 = ls[wv][lane * 4 + 2], s3 = ls[wv][lane * 4 + 3];
    int s = s0 + s1 + s2 + s3;
    int incl = s;
#pragma unroll
    for (int d = 1; d < 64; d <<= 1) {
      int tsh = __shfl_up(incl, d, 64);
      if (lane >= d) incl += tsh;
    }
    int excl = incl - s;
    ls[wv][lane * 4 + 0] = excl;
    ls[wv][lane * 4 + 1] = excl + s0;
    ls[wv][lane * 4 + 2] = excl + s0 + s1;
    ls[wv][lane * 4 + 3] = excl + s0 + s1 + s2;
    if (lane == 63) lt[wv] = incl;
  }
  __syncthreads();
  if (tid == 0) {
    int o = 0;
#pragma unroll
    for (int e = 0; e < 4; ++e) {
      lo[e] = o; offs[e] = o; counts[e] = lt[e];
      o += (lt[e] + 127) & ~127;
    }
    lo[4] = o; offs[4] = o;
  }
  __syncthreads();
  int b0 = lo[0] + ls[0][tid], b1 = lo[1] + ls[1][tid];
  int b2 = lo[2] + ls[2][tid], b3 = lo[3] + ls[3][tid];
#pragma unroll
  for (int j = 0; j < 32; ++j) {
    int p = pe[j];
    int t = t0 + j;
    int e1 = p & 255, e2 = p >> 8;
    int s1 = (e1 == 0) ? b0 : (e1 == 1) ? b1 : (e1 == 2) ? b2 : b3;
    tok[s1] = t;
    b0 += (e1 == 0); b1 += (e1 == 1); b2 += (e1 == 2); b3 += (e1 == 3);
    int s2 = (e2 == 0) ? b0 : (e2 == 1) ? b1 : (e2 == 2) ? b2 : b3;
    tok[s2] = t;
    b0 += (e2 == 0); b1 += (e2 == 1); b2 += (e2 == 2); b3 += (e2 == 3);
    e12[t] = s1 | (s2 << 16);   // sl12: this thread's own token range only
  }
  // zero-fill pad tok slots (safe gload addresses)
#pragma unroll
  for (int e = 0; e < 4; ++e) {
    int start = lo[e] + lt[e];
    int end = lo[e + 1];
    for (int i = start + tid; i < end; i += 256) tok[i] = 0;
  }
}

// XOR-swizzled LDS fragment read (zero bank conflicts)
__device__ __forceinline__ f16x8 lds_frag(const char* base, int row, int kbyte) {
  return *(const f16x8*)(base + row * 128 + (kbyte ^ ((row & 7) << 4)));
}

#define GVM6   asm volatile("s_waitcnt vmcnt(6)" ::: "memory")
#define GVM8   asm volatile("s_waitcnt vmcnt(8)" ::: "memory")
#define GVM0   asm volatile("s_waitcnt vmcnt(0)" ::: "memory")
#define GBAR   asm volatile("s_barrier" ::: "memory")
#define GLGKM  asm volatile("s_waitcnt lgkmcnt(0)" ::: "memory")

// ---- kernel 3: GEMM1 (blocks 0..2111) + W2^T riders (2112..3135, 4 tiles each) ----
// GEMM1: 128x256, 512 thr (2Mx4N waves), K=1024, LDS dbuf 96KB, counted vmcnt(6).
// A gathered from x16 via tok (per-lane global src); operands L2/L3-hot.
__global__ __launch_bounds__(512) void gemm1x_k(
    const _Float16* __restrict__ x16, const _Float16* __restrict__ B,
    const float* __restrict__ bias, const int* __restrict__ offs,
    const int* __restrict__ counts, const int* __restrict__ tok,
    _Float16* __restrict__ outH,
    const float* __restrict__ W2, _Float16* __restrict__ W2f) {
  extern __shared__ char smem[];
  int bid = blockIdx.x;
  if (bid >= 2112) {
    // W2^T riders: 4 tiles per block (2 halves x 2 reps). K=4096, N=1024.
    int half = threadIdx.x >> 8;
    int t = threadIdx.x & 255;
    float (*tile)[65] = (float(*)[65])(smem + half * 16640);
    int base = (bid - 2112) * 4 + half * 2;
#pragma unroll
    for (int rep = 0; rep < 2; ++rep) {
      int T = base + rep;   // 0..4095
      int n0 = (T & 15) * 64, k0 = ((T >> 4) & 63) * 64, e = T >> 10;
      wtrans_body(W2, W2f, 4096, 1024, e, n0, k0, t, tile);
    }
    return;
  }
  // nwg = 2112; bijective XCD swizzle: q=264
  int wg = (bid & 7) * 264 + (bid >> 3);
  int col = wg & 15, row = wg >> 4;       // col-fastest
  int rowBase = row * 128;
  if (rowBase >= offs[4]) return;
  int e = 0;
  while (e < 3 && rowBase >= offs[e + 1]) ++e;
  if (rowBase >= offs[e] + counts[e]) return;
  int colBase = col * 256;

  int tid = threadIdx.x, wid = tid >> 6, lane = tid & 63;
  int wr = wid >> 2, wc = wid & 3;        // 2M x 4N
  int ln = lane & 15;
  int srow = lane >> 3;
  int kx = (lane & 7) ^ srow;
  // per-thread A bases: 2 chunks (16 chunks over 8 waves), token-indirect
  const _Float16* Asrc[2];
#pragma unroll
  for (int i = 0; i < 2; ++i) {
    int tk = tok[rowBase + (wid * 2 + i) * 8 + srow];
    Asrc[i] = x16 + (size_t)tk * 1024 + kx * 8;
  }
  const _Float16* Bbase = B + (size_t)e * D_FF * 1024 + (size_t)colBase * 1024 + kx * 8;

  f32x4 acc[4][4];
  f32x4 zero = {0.f, 0.f, 0.f, 0.f};
#pragma unroll
  for (int m = 0; m < 4; ++m)
#pragma unroll
    for (int n = 0; n < 4; ++n) acc[m][n] = zero;

  // stage K-tile kt into buffer b (A 16KB @0, B 32KB @16384; buffers 48KB apart)
  auto STAGE = [&](int kt, int b) {
    char* lA = smem + b * 49152;
    char* lB = lA + 16384;
    int k0 = kt * 64;
#pragma unroll
    for (int i = 0; i < 2; ++i)
      gload_lds16(Asrc[i] + k0, lA + (wid * 2 + i) * 1024);
#pragma unroll
    for (int i = 0; i < 4; ++i) {
      int chunk = wid * 4 + i;
      gload_lds16(Bbase + (size_t)(chunk * 8 + srow) * 1024 + k0, lB + chunk * 1024);
    }
  };

  STAGE(0, 0);
  STAGE(1, 1);
  // invariant: 2 tiles (12 loads/thread) outstanding; vmcnt(6) retires tile t.

  for (int t = 0; t < 16; ++t) {
    GVM6;
    GBAR;
    const char* cA = smem + (t & 1) * 49152;
    const char* cB = cA + 16384;
#pragma unroll
    for (int kk = 0; kk < 2; ++kk) {
      int kbyte = kk * 64 + (lane >> 4) * 16;
      f16x8 af[4], bf[4];
#pragma unroll
      for (int m = 0; m < 4; ++m)
        af[m] = lds_frag(cA, wr * 64 + m * 16 + ln, kbyte);
#pragma unroll
      for (int n = 0; n < 4; ++n)
        bf[n] = lds_frag(cB, wc * 64 + n * 16 + ln, kbyte);
      GLGKM;
      __builtin_amdgcn_s_setprio(1);
#pragma unroll
      for (int m = 0; m < 4; ++m)
#pragma unroll
        for (int n = 0; n < 4; ++n)
          acc[m][n] = __builtin_amdgcn_mfma_f32_16x16x32_f16(af[m], bf[n], acc[m][n], 0, 0, 0);
      __builtin_amdgcn_s_setprio(0);
    }
    GBAR;
    int tn = t + 2; if (tn > 15) tn = 15;   // clamped dummy restage (L2-hot)
    STAGE(tn, t & 1);
  }
  GVM0;

  int col0 = colBase + wc * 64 + ln;
  float bv[4];
#pragma unroll
  for (int n = 0; n < 4; ++n) bv[n] = bias[(size_t)e * D_FF + col0 + n * 16];
#pragma unroll
  for (int m = 0; m < 4; ++m) {
    int rbase = rowBase + wr * 64 + m * 16 + (lane >> 4) * 4;
#pragma unroll
    for (int j = 0; j < 4; ++j) {
      size_t ro = (size_t)(rbase + j) * D_FF;
#pragma unroll
      for (int n = 0; n < 4; ++n) {
        float v = fast_gelu(acc[m][n][j] + bv[n]);
        outH[ro + col0 + n * 16] = (_Float16)v;
      }
    }
  }
}

// ---- kernel 4: GEMM2 128x128, K=4096, LDS dbuf 64KB + counted vmcnt (r12, best) ----
__global__ __launch_bounds__(256, 2) void gemm2_k(
    const _Float16* __restrict__ A, const _Float16* __restrict__ B,
    const float* __restrict__ bias, const int* __restrict__ offs,
    const int* __restrict__ counts, _Float16* __restrict__ Eout) {
  __shared__ char lds[65536];
  // nwg = 132*8 = 1056; bijective XCD swizzle: q=132
  int bid = blockIdx.x;
  int wg = (bid & 7) * 132 + (bid >> 3);
  int col = wg & 7, row = wg >> 3;        // col-fastest
  int rowBase = row * 128;
  if (rowBase >= offs[4]) return;
  int e = 0;
  while (e < 3 && rowBase >= offs[e + 1]) ++e;
  int eoff = offs[e], cnt = counts[e];
  if (rowBase >= eoff + cnt) return;
  int colBase = col * 128;

  int tid = threadIdx.x, wid = tid >> 6, lane = tid & 63;
  int wr = wid >> 1, wc = wid & 1;
  int ln = lane & 15;
  int srow = lane >> 3;
  int kx = (lane & 7) ^ srow;
  const _Float16* Abase = A + (size_t)rowBase * 4096 + kx * 8;
  const _Float16* Bbase = B + (size_t)e * D_MODEL * 4096 + (size_t)colBase * 4096 + kx * 8;

  f32x4 acc[4][4];
  f32x4 zero = {0.f, 0.f, 0.f, 0.f};
#pragma unroll
  for (int m = 0; m < 4; ++m)
#pragma unroll
    for (int n = 0; n < 4; ++n) acc[m][n] = zero;

  auto STAGE = [&](int kt, int b) {
    char* lA = lds + (b << 15);
    char* lB = lA + 16384;
    int k0 = kt * 64;
#pragma unroll
    for (int i = 0; i < 4; ++i) {
      int chunk = wid * 4 + i;
      gload_lds16(Abase + (size_t)(chunk * 8 + srow) * 4096 + k0, lA + chunk * 1024);
      gload_lds16(Bbase + (size_t)(chunk * 8 + srow) * 4096 + k0, lB + chunk * 1024);
    }
  };

  STAGE(0, 0);
  STAGE(1, 1);

  for (int t = 0; t < 64; ++t) {
    GVM8;
    GBAR;
    const char* cA = lds + ((t & 1) << 15);
    const char* cB = cA + 16384;
#pragma unroll
    for (int kk = 0; kk < 2; ++kk) {
      int kbyte = kk * 64 + (lane >> 4) * 16;
      f16x8 af[4], bf[4];
#pragma unroll
      for (int m = 0; m < 4; ++m)
        af[m] = lds_frag(cA, wr * 64 + m * 16 + ln, kbyte);
#pragma unroll
      for (int n = 0; n < 4; ++n)
        bf[n] = lds_frag(cB, wc * 64 + n * 16 + ln, kbyte);
      GLGKM;
      __builtin_amdgcn_s_setprio(1);
#pragma unroll
      for (int m = 0; m < 4; ++m)
#pragma unroll
        for (int n = 0; n < 4; ++n)
          acc[m][n] = __builtin_amdgcn_mfma_f32_16x16x32_f16(af[m], bf[n], acc[m][n], 0, 0, 0);
      __builtin_amdgcn_s_setprio(0);
    }
    GBAR;
    int tn = t + 2; if (tn > 63) tn = 63;
    STAGE(tn, t & 1);
  }
  GVM0;

  int col0 = colBase + wc * 64 + ln;
  float bv[4];
#pragma unroll
  for (int n = 0; n < 4; ++n) bv[n] = bias[(size_t)e * D_MODEL + col0 + n * 16];
#pragma unroll
  for (int m = 0; m < 4; ++m) {
    int rbase = rowBase + wr * 64 + m * 16 + (lane >> 4) * 4;
#pragma unroll
    for (int j = 0; j < 4; ++j) {
      int grow = rbase + j;
      if (grow - eoff < cnt) {
        size_t o = (size_t)grow * D_MODEL + col0;
#pragma unroll
        for (int n = 0; n < 4; ++n)
          Eout[o + n * 16] = (_Float16)(acc[m][n][j] + bv[n]);
      }
    }
  }
}

// ---- kernel 5: combine out[t] = w1*Eout[s1] + w2*Eout[s2] ----
__global__ __launch_bounds__(256) void combine_k(
    const _Float16* __restrict__ Eout, const int* __restrict__ sl12,
    const float* __restrict__ w12, float* __restrict__ out) {
  int t = blockIdx.x * 2 + (threadIdx.x >> 7);
  int tid = threadIdx.x & 127;
  int p = sl12[t];
  int s1 = p & 0xffff, s2 = (p >> 16) & 0xffff;
  float w1 = w12[2 * t], w2 = w12[2 * t + 1];
  f16x8 a = *(const f16x8*)(Eout + (size_t)s1 * D_MODEL + tid * 8);
  f16x8 b = *(const f16x8*)(Eout + (size_t)s2 * D_MODEL + tid * 8);
  fvec4 o0, o1;
#pragma unroll
  for (int j = 0; j < 4; ++j) {
    o0[j] = w1 * (float)a[j] + w2 * (float)b[j];
    o1[j] = w1 * (float)a[4 + j] + w2 * (float)b[4 + j];
  }
  float* dst = out + (size_t)t * D_MODEL + tid * 8;
  *(fvec4*)dst = o0;
  *(fvec4*)(dst + 4) = o1;
}

extern "C" void kernel_launch(void* const* d_in, const int* in_sizes, int n_in,
                              void* d_out, int out_size, void* d_ws, size_t ws_size,
                              hipStream_t stream) {
  const float* x  = (const float*)d_in[0];
  const float* Wr = (const float*)d_in[1];
  const float* br = (const float*)d_in[2];
  const float* W1 = (const float*)d_in[3];
  const float* b1 = (const float*)d_in[4];
  const float* W2 = (const float*)d_in[5];
  const float* b2 = (const float*)d_in[6];
  float* out = (float*)d_out;
  char* ws = (char*)d_ws;
  if (ws_size < WS_NEED) return;

  _Float16* W1f = (_Float16*)(ws + OFF_W1);
  _Float16* W2f = (_Float16*)(ws + OFF_W2);
  _Float16* x16 = (_Float16*)(ws + OFF_XG);   // x16 first; Eout reuses region after gemm1
  _Float16* H   = (_Float16*)(ws + OFF_H);
  int*   counts = (int*)(ws + OFF_CNT);
  int*   offs   = (int*)(ws + OFF_OFS);
  int*   tok    = (int*)(ws + OFF_TOK);
  int*   e12    = (int*)(ws + OFF_E12);       // becomes sl12 after plan_k
  float* w12    = (float*)(ws + OFF_W12);
  _Float16* Eout = x16;                        // stream-ordered reuse: x16 dead after gemm1

  hipFuncSetAttribute((const void*)gemm1x_k,
                      hipFuncAttributeMaxDynamicSharedMemorySize, 98304);

  rwc_k<<<10240, 256, 0, stream>>>(x, Wr, br, e12, w12, W1, W1f, x16);
  plan_k<<<1, 256, 0, stream>>>(e12, w12, counts, offs, tok);
  gemm1x_k<<<3136, 512, 98304, stream>>>(x16, W1f, b1, offs, counts, tok, H, W2, W2f);
  gemm2_k<<<NRB * 8, 256, 0, stream>>>(H, W2f, b2, offs, counts, Eout);
  combine_k<<<NTOK / 2, 256, 0, stream>>>(Eout, e12, w12, out);
}

// Round 14
// 434.205 us; speedup vs baseline: 1.0989x; 1.0989x over previous
//
#include <hip/hip_runtime.h>
#include <hip/hip_bf16.h>
#include <hip/hip_fp16.h>
#include <stdint.h>

typedef float    f32x4 __attribute__((ext_vector_type(4)));
typedef float    fvec4 __attribute__((ext_vector_type(4)));
typedef _Float16 f16x8 __attribute__((ext_vector_type(8)));
typedef _Float16 f16x4 __attribute__((ext_vector_type(4)));

#define D_MODEL 1024
#define D_FF    4096
#define NTOK    8192
#define CAP_ROWS 16896  // 132 * 128
#define NRB      132    // row blocks of 128

// ---- workspace layout (bytes) ----
#define OFF_W1  0UL           // 4*4096*1024*2 (W1^T fp16: [e][n][k])
#define OFF_W2  33554432UL    // 4*1024*4096*2 (W2^T fp16: [e][d][f])
#define OFF_XG  67108864UL    // x16 [8192][1024] fp16 (16MB); then Eout [CAP_ROWS][1024] fp16
#define OFF_H   101711872UL   // 16896*4096*2
#define OFF_CNT 240123904UL
#define OFF_OFS 240123936UL
#define OFF_TOK 240124160UL
#define OFF_E12 240259328UL   // e12 during routing; rewritten as sl12 by plan_k
#define OFF_W12 240292096UL
#define WS_NEED 240357632UL

__device__ __forceinline__ void gload_lds16(const void* g, void* l) {
  __builtin_amdgcn_global_load_lds(
      (const __attribute__((address_space(1))) unsigned int*)g,
      (__attribute__((address_space(3))) unsigned int*)l, 16, 0, 0);
}

// fast tanh-approx GELU (inf-safe), max err ~3e-4
__device__ __forceinline__ float fast_gelu(float v) {
  float v2 = v * v;
  float y2 = v * (2.302118131f + 0.10293924f * v2);
  float t = exp2f(y2);
  return v - v * __builtin_amdgcn_rcpf(1.f + t);
}

// shared transpose-convert body: in[e][K][N] fp32 -> out[e][N][K] fp16 (256 threads)
__device__ __forceinline__ void wtrans_body(
    const float* __restrict__ in, _Float16* __restrict__ out,
    int K, int N, int e, int n0, int k0, float (*tile)[65]) {
  const float* src = in + (size_t)e * K * N;
  _Float16* dst = out + (size_t)e * K * N;
  int t = threadIdx.x;
  {
    int kk = t >> 2, nc = (t & 3) * 16;
    const float* p = src + (size_t)(k0 + kk) * N + n0 + nc;
#pragma unroll
    for (int j = 0; j < 4; ++j) {
      fvec4 v = *(const fvec4*)(p + j * 4);
      tile[kk][nc + j * 4 + 0] = v[0]; tile[kk][nc + j * 4 + 1] = v[1];
      tile[kk][nc + j * 4 + 2] = v[2]; tile[kk][nc + j * 4 + 3] = v[3];
    }
  }
  __syncthreads();
  {
    int nn = t >> 2, kb = (t & 3) * 16;
    f16x8 o0, o1;
#pragma unroll
    for (int j = 0; j < 8; ++j) o0[j] = (_Float16)tile[kb + j][nn];
#pragma unroll
    for (int j = 0; j < 8; ++j) o1[j] = (_Float16)tile[kb + 8 + j][nn];
    _Float16* q = dst + (size_t)(n0 + nn) * K + k0 + kb;
    *(f16x8*)q = o0;
    *((f16x8*)q + 1) = o1;
  }
}

// ---- kernel 1: router+cvt fused (blocks 0..2047) + W1^T (2048..6143) ----
// Router wave holds the full token row in registers -> convert+store x16 inline
// (x read ONCE from HBM instead of twice).
__global__ __launch_bounds__(256) void rwc_k(
    const float* __restrict__ x, const float* __restrict__ Wr,
    const float* __restrict__ br, int* __restrict__ e12,
    float* __restrict__ w12,
    const float* __restrict__ W1, _Float16* __restrict__ W1f,
    _Float16* __restrict__ x16) {
  __shared__ float tile[64][65];
  int b = blockIdx.x;
  if (b >= 2048) {
    int bb = b - 2048;   // W1: K=1024, N=4096; 64(n) x 16(k) x 4(e)
    int n0 = (bb & 63) * 64, k0 = ((bb >> 6) & 15) * 64, e = bb >> 10;
    wtrans_body(W1, W1f, 1024, 4096, e, n0, k0, tile);
    return;
  }
  int wid = threadIdx.x >> 6, lane = threadIdx.x & 63;
  int t = b * 4 + wid;
  const float* xr = x + (size_t)t * D_MODEL;
  _Float16* xw = x16 + (size_t)t * D_MODEL;
  float a0 = 0.f, a1 = 0.f, a2 = 0.f, a3 = 0.f;
#pragma unroll
  for (int c = 0; c < 4; ++c) {
    int d0 = c * 256 + lane * 4;
    fvec4 xv = *(const fvec4*)(xr + d0);
    // fused fp16 convert-store (8B/lane, coalesced within the wave)
    f16x4 o = {(_Float16)xv[0], (_Float16)xv[1], (_Float16)xv[2], (_Float16)xv[3]};
    *(f16x4*)(xw + d0) = o;
#pragma unroll
    for (int j = 0; j < 4; ++j) {
      fvec4 wv = *(const fvec4*)(Wr + (size_t)(d0 + j) * 4);
      a0 += xv[j] * wv[0]; a1 += xv[j] * wv[1];
      a2 += xv[j] * wv[2]; a3 += xv[j] * wv[3];
    }
  }
#pragma unroll
  for (int m = 32; m; m >>= 1) {
    a0 += __shfl_xor(a0, m, 64); a1 += __shfl_xor(a1, m, 64);
    a2 += __shfl_xor(a2, m, 64); a3 += __shfl_xor(a3, m, 64);
  }
  if (lane == 0) {
    float l[4] = {a0 + br[0], a1 + br[1], a2 + br[2], a3 + br[3]};
    int e1 = 0; float m1 = l[0];
#pragma unroll
    for (int e = 1; e < 4; ++e) if (l[e] > m1) { m1 = l[e]; e1 = e; }
    int e2 = -1; float m2 = -1e30f;
#pragma unroll
    for (int e = 0; e < 4; ++e) if (e != e1 && l[e] > m2) { m2 = l[e]; e2 = e; }
    float tt = expf(m2 - m1);
    float w1 = 1.f / (1.f + tt), w2 = tt / (1.f + tt);
    e12[t] = e1 | (e2 << 8);
    w12[2 * t] = w1; w12[2 * t + 1] = w2;
  }
}

// ---- kernel 2: plan (deterministic; writes sl12 into e12 buf; zero-fills pad tok) ----
__global__ __launch_bounds__(256) void plan_k(
    int* __restrict__ e12, const float* __restrict__ w12,
    int* __restrict__ counts, int* __restrict__ offs,
    int* __restrict__ tok) {
  __shared__ int ls[4][256];
  __shared__ int lt[4];
  __shared__ int lo[5];
  int tid = threadIdx.x;
  int t0 = tid * 32;
  int pe[32];
  int c0 = 0, c1 = 0, c2 = 0, c3 = 0;
#pragma unroll
  for (int j = 0; j < 32; ++j) {
    int p = e12[t0 + j];
    pe[j] = p;
    int e1 = p & 255, e2 = p >> 8;
    c0 += (e1 == 0) + (e2 == 0);
    c1 += (e1 == 1) + (e2 == 1);
    c2 += (e1 == 2) + (e2 == 2);
    c3 += (e1 == 3) + (e2 == 3);
  }
  ls[0][tid] = c0; ls[1][tid] = c1; ls[2][tid] = c2; ls[3][tid] = c3;
  __syncthreads();
  int wv = tid >> 6, lane = tid & 63;
  {
    int s0 = ls[wv][lane * 4 + 0], s1 = ls[wv][lane * 4 + 1];
    int s2 = ls[wv][lane * 4 + 2], s3 = ls[wv][lane * 4 + 3];
    int s = s0 + s1 + s2 + s3;
    int incl = s;
#pragma unroll
    for (int d = 1; d < 64; d <<= 1) {
      int tsh = __shfl_up(incl, d, 64);
      if (lane >= d) incl += tsh;
    }
    int excl = incl - s;
    ls[wv][lane * 4 + 0] = excl;
    ls[wv][lane * 4 + 1] = excl + s0;
    ls[wv][lane * 4 + 2] = excl + s0 + s1;
    ls[wv][lane * 4 + 3] = excl + s0 + s1 + s2;
    if (lane == 63) lt[wv] = incl;
  }
  __syncthreads();
  if (tid == 0) {
    int o = 0;
#pragma unroll
    for (int e = 0; e < 4; ++e) {
      lo[e] = o; offs[e] = o; counts[e] = lt[e];
      o += (lt[e] + 127) & ~127;
    }
    lo[4] = o; offs[4] = o;
  }
  __syncthreads();
  int b0 = lo[0] + ls[0][tid], b1 = lo[1] + ls[1][tid];
  int b2 = lo[2] + ls[2][tid], b3 = lo[3] + ls[3][tid];
#pragma unroll
  for (int j = 0; j < 32; ++j) {
    int p = pe[j];
    int t = t0 + j;
    int e1 = p & 255, e2 = p >> 8;
    int s1 = (e1 == 0) ? b0 : (e1 == 1) ? b1 : (e1 == 2) ? b2 : b3;
    tok[s1] = t;
    b0 += (e1 == 0); b1 += (e1 == 1); b2 += (e1 == 2); b3 += (e1 == 3);
    int s2 = (e2 == 0) ? b0 : (e2 == 1) ? b1 : (e2 == 2) ? b2 : b3;
    tok[s2] = t;
    b0 += (e2 == 0); b1 += (e2 == 1); b2 += (e2 == 2); b3 += (e2 == 3);
    e12[t] = s1 | (s2 << 16);   // sl12: this thread's own token range only
  }
  // zero-fill pad tok slots (safe gload addresses)
#pragma unroll
  for (int e = 0; e < 4; ++e) {
    int start = lo[e] + lt[e];
    int end = lo[e + 1];
    for (int i = start + tid; i < end; i += 256) tok[i] = 0;
  }
}

// XOR-swizzled LDS fragment read (zero bank conflicts)
__device__ __forceinline__ f16x8 lds_frag(const char* base, int row, int kbyte) {
  return *(const f16x8*)(base + row * 128 + (kbyte ^ ((row & 7) << 4)));
}

#define GVM8   asm volatile("s_waitcnt vmcnt(8)" ::: "memory")
#define GVM0   asm volatile("s_waitcnt vmcnt(0)" ::: "memory")
#define GBAR   asm volatile("s_barrier" ::: "memory")
#define GLGKM  asm volatile("s_waitcnt lgkmcnt(0)" ::: "memory")

// ---- kernel 3: GEMM1 (blocks 0..2111, A gathered from x16 via tok) + W2^T (2112..6207) ----
// r12-measured-best: 128x256, 4 waves, 48KB LDS, __syncthreads loop. (dbuf port regressed r13)
__global__ __launch_bounds__(256, 2) void gemm1x_k(
    const _Float16* __restrict__ x16, const _Float16* __restrict__ B,
    const float* __restrict__ bias, const int* __restrict__ offs,
    const int* __restrict__ counts, const int* __restrict__ tok,
    _Float16* __restrict__ outH,
    const float* __restrict__ W2, _Float16* __restrict__ W2f) {
  __shared__ char lds[49152];
  int bid = blockIdx.x;
  if (bid >= 2112) {
    int bb = bid - 2112;  // W2: K=4096, N=1024; 16(n) x 64(k) x 4(e)
    int n0 = (bb & 15) * 64, k0 = ((bb >> 4) & 63) * 64, e = bb >> 10;
    wtrans_body(W2, W2f, 4096, 1024, e, n0, k0, (float(*)[65])lds);
    return;
  }
  // nwg = 2112; bijective XCD swizzle: q=264
  int wg = (bid & 7) * 264 + (bid >> 3);
  int col = wg & 15, row = wg >> 4;       // col-fastest
  int rowBase = row * 128;
  if (rowBase >= offs[4]) return;
  int e = 0;
  while (e < 3 && rowBase >= offs[e + 1]) ++e;
  if (rowBase >= offs[e] + counts[e]) return;
  int colBase = col * 256;

  int tid = threadIdx.x, wid = tid >> 6, lane = tid & 63;
  int wr = wid >> 1, wc = wid & 1;
  int ln = lane & 15;
  int srow = lane >> 3;
  int kx = (lane & 7) ^ srow;
  const _Float16* Asrc[4];
#pragma unroll
  for (int i = 0; i < 4; ++i) {
    int tk = tok[rowBase + (wid * 4 + i) * 8 + srow];
    Asrc[i] = x16 + (size_t)tk * 1024 + kx * 8;
  }
  const _Float16* Bbase = B + (size_t)e * D_FF * 1024 + (size_t)colBase * 1024 + kx * 8;
  char* ldsA = lds;
  char* ldsB = lds + 16384;

  f32x4 acc[4][8];
  f32x4 zero = {0.f, 0.f, 0.f, 0.f};
#pragma unroll
  for (int m = 0; m < 4; ++m)
#pragma unroll
    for (int n = 0; n < 8; ++n) acc[m][n] = zero;

  for (int k0 = 0; k0 < 1024; k0 += 64) {
#pragma unroll
    for (int i = 0; i < 4; ++i) {
      int chunk = wid * 4 + i;
      gload_lds16(Asrc[i] + k0, ldsA + chunk * 1024);
    }
#pragma unroll
    for (int i = 0; i < 8; ++i) {
      int chunk = wid * 8 + i;
      gload_lds16(Bbase + (size_t)(chunk * 8 + srow) * 1024 + k0, ldsB + chunk * 1024);
    }
    __syncthreads();
#pragma unroll
    for (int kk = 0; kk < 2; ++kk) {
      int kbyte = kk * 64 + (lane >> 4) * 16;
      f16x8 af[4], bf[8];
#pragma unroll
      for (int m = 0; m < 4; ++m)
        af[m] = lds_frag(ldsA, wr * 64 + m * 16 + ln, kbyte);
#pragma unroll
      for (int n = 0; n < 8; ++n)
        bf[n] = lds_frag(ldsB, wc * 128 + n * 16 + ln, kbyte);
#pragma unroll
      for (int m = 0; m < 4; ++m)
#pragma unroll
        for (int n = 0; n < 8; ++n)
          acc[m][n] = __builtin_amdgcn_mfma_f32_16x16x32_f16(af[m], bf[n], acc[m][n], 0, 0, 0);
    }
    __syncthreads();
  }

  int col0 = colBase + wc * 128 + ln;
  float bv[8];
#pragma unroll
  for (int n = 0; n < 8; ++n) bv[n] = bias[(size_t)e * D_FF + col0 + n * 16];
#pragma unroll
  for (int m = 0; m < 4; ++m) {
    int rbase = rowBase + wr * 64 + m * 16 + (lane >> 4) * 4;
#pragma unroll
    for (int j = 0; j < 4; ++j) {
      size_t ro = (size_t)(rbase + j) * D_FF;
#pragma unroll
      for (int n = 0; n < 8; ++n) {
        float v = fast_gelu(acc[m][n][j] + bv[n]);
        outH[ro + col0 + n * 16] = (_Float16)v;
      }
    }
  }
}

// ---- kernel 4: GEMM2 128x128, K=4096, LDS dbuf 64KB + counted vmcnt (r12, best) ----
__global__ __launch_bounds__(256, 2) void gemm2_k(
    const _Float16* __restrict__ A, const _Float16* __restrict__ B,
    const float* __restrict__ bias, const int* __restrict__ offs,
    const int* __restrict__ counts, _Float16* __restrict__ Eout) {
  __shared__ char lds[65536];
  // nwg = 132*8 = 1056; bijective XCD swizzle: q=132
  int bid = blockIdx.x;
  int wg = (bid & 7) * 132 + (bid >> 3);
  int col = wg & 7, row = wg >> 3;        // col-fastest
  int rowBase = row * 128;
  if (rowBase >= offs[4]) return;
  int e = 0;
  while (e < 3 && rowBase >= offs[e + 1]) ++e;
  int eoff = offs[e], cnt = counts[e];
  if (rowBase >= eoff + cnt) return;
  int colBase = col * 128;

  int tid = threadIdx.x, wid = tid >> 6, lane = tid & 63;
  int wr = wid >> 1, wc = wid & 1;
  int ln = lane & 15;
  int srow = lane >> 3;
  int kx = (lane & 7) ^ srow;
  const _Float16* Abase = A + (size_t)rowBase * 4096 + kx * 8;
  const _Float16* Bbase = B + (size_t)e * D_MODEL * 4096 + (size_t)colBase * 4096 + kx * 8;

  f32x4 acc[4][4];
  f32x4 zero = {0.f, 0.f, 0.f, 0.f};
#pragma unroll
  for (int m = 0; m < 4; ++m)
#pragma unroll
    for (int n = 0; n < 4; ++n) acc[m][n] = zero;

  auto STAGE = [&](int kt, int b) {
    char* lA = lds + (b << 15);
    char* lB = lA + 16384;
    int k0 = kt * 64;
#pragma unroll
    for (int i = 0; i < 4; ++i) {
      int chunk = wid * 4 + i;
      gload_lds16(Abase + (size_t)(chunk * 8 + srow) * 4096 + k0, lA + chunk * 1024);
      gload_lds16(Bbase + (size_t)(chunk * 8 + srow) * 4096 + k0, lB + chunk * 1024);
    }
  };

  STAGE(0, 0);
  STAGE(1, 1);
  // invariant at top of iter t: 2 tiles (16 loads) outstanding; vmcnt(8) retires tile t.

  for (int t = 0; t < 64; ++t) {
    GVM8;
    GBAR;
    const char* cA = lds + ((t & 1) << 15);
    const char* cB = cA + 16384;
#pragma unroll
    for (int kk = 0; kk < 2; ++kk) {
      int kbyte = kk * 64 + (lane >> 4) * 16;
      f16x8 af[4], bf[4];
#pragma unroll
      for (int m = 0; m < 4; ++m)
        af[m] = lds_frag(cA, wr * 64 + m * 16 + ln, kbyte);
#pragma unroll
      for (int n = 0; n < 4; ++n)
        bf[n] = lds_frag(cB, wc * 64 + n * 16 + ln, kbyte);
      GLGKM;
      __builtin_amdgcn_s_setprio(1);
#pragma unroll
      for (int m = 0; m < 4; ++m)
#pragma unroll
        for (int n = 0; n < 4; ++n)
          acc[m][n] = __builtin_amdgcn_mfma_f32_16x16x32_f16(af[m], bf[n], acc[m][n], 0, 0, 0);
      __builtin_amdgcn_s_setprio(0);
    }
    GBAR;
    int tn = t + 2; if (tn > 63) tn = 63;   // clamped dummy restage keeps vmcnt uniform
    STAGE(tn, t & 1);
  }
  GVM0;

  int col0 = colBase + wc * 64 + ln;
  float bv[4];
#pragma unroll
  for (int n = 0; n < 4; ++n) bv[n] = bias[(size_t)e * D_MODEL + col0 + n * 16];
#pragma unroll
  for (int m = 0; m < 4; ++m) {
    int rbase = rowBase + wr * 64 + m * 16 + (lane >> 4) * 4;
#pragma unroll
    for (int j = 0; j < 4; ++j) {
      int grow = rbase + j;
      if (grow - eoff < cnt) {
        size_t o = (size_t)grow * D_MODEL + col0;
#pragma unroll
        for (int n = 0; n < 4; ++n)
          Eout[o + n * 16] = (_Float16)(acc[m][n][j] + bv[n]);
      }
    }
  }
}

// ---- kernel 5: combine out[t] = w1*Eout[s1] + w2*Eout[s2] ----
__global__ __launch_bounds__(256) void combine_k(
    const _Float16* __restrict__ Eout, const int* __restrict__ sl12,
    const float* __restrict__ w12, float* __restrict__ out) {
  int t = blockIdx.x * 2 + (threadIdx.x >> 7);
  int tid = threadIdx.x & 127;
  int p = sl12[t];
  int s1 = p & 0xffff, s2 = (p >> 16) & 0xffff;
  float w1 = w12[2 * t], w2 = w12[2 * t + 1];
  f16x8 a = *(const f16x8*)(Eout + (size_t)s1 * D_MODEL + tid * 8);
  f16x8 b = *(const f16x8*)(Eout + (size_t)s2 * D_MODEL + tid * 8);
  fvec4 o0, o1;
#pragma unroll
  for (int j = 0; j < 4; ++j) {
    o0[j] = w1 * (float)a[j] + w2 * (float)b[j];
    o1[j] = w1 * (float)a[4 + j] + w2 * (float)b[4 + j];
  }
  float* dst = out + (size_t)t * D_MODEL + tid * 8;
  *(fvec4*)dst = o0;
  *(fvec4*)(dst + 4) = o1;
}

extern "C" void kernel_launch(void* const* d_in, const int* in_sizes, int n_in,
                              void* d_out, int out_size, void* d_ws, size_t ws_size,
                              hipStream_t stream) {
  const float* x  = (const float*)d_in[0];
  const float* Wr = (const float*)d_in[1];
  const float* br = (const float*)d_in[2];
  const float* W1 = (const float*)d_in[3];
  const float* b1 = (const float*)d_in[4];
  const float* W2 = (const float*)d_in[5];
  const float* b2 = (const float*)d_in[6];
  float* out = (float*)d_out;
  char* ws = (char*)d_ws;
  if (ws_size < WS_NEED) return;

  _Float16* W1f = (_Float16*)(ws + OFF_W1);
  _Float16* W2f = (_Float16*)(ws + OFF_W2);
  _Float16* x16 = (_Float16*)(ws + OFF_XG);   // x16 first; Eout reuses region after gemm1
  _Float16* H   = (_Float16*)(ws + OFF_H);
  int*   counts = (int*)(ws + OFF_CNT);
  int*   offs   = (int*)(ws + OFF_OFS);
  int*   tok    = (int*)(ws + OFF_TOK);
  int*   e12    = (int*)(ws + OFF_E12);       // becomes sl12 after plan_k
  float* w12    = (float*)(ws + OFF_W12);
  _Float16* Eout = x16;                        // stream-ordered reuse: x16 dead after gemm1

  rwc_k<<<6144, 256, 0, stream>>>(x, Wr, br, e12, w12, W1, W1f, x16);
  plan_k<<<1, 256, 0, stream>>>(e12, w12, counts, offs, tok);
  gemm1x_k<<<6208, 256, 0, stream>>>(x16, W1f, b1, offs, counts, tok, H, W2, W2f);
  gemm2_k<<<NRB * 8, 256, 0, stream>>>(H, W2f, b2, offs, counts, Eout);
  combine_k<<<NTOK / 2, 256, 0, stream>>>(Eout, e12, w12, out);
}